// Round 5
// baseline (1074.678 us; speedup 1.0000x reference)
//
#include <hip/hip_runtime.h>
#include <hip/hip_bf16.h>

#define N_NODES 50000
#define N_EDGES 800000
#define D       64
#define HID     256
#define DIN     128   // 2*D
#define NB      32    // nodes per block in fallback fused MLP

#define MB1     64    // nodes per block, gemm1
#define KC1     32    // k-chunk, gemm1
#define MB2     64    // nodes per block, gemm2
#define KC2     32    // k-chunk, gemm2

// aggregation params
#define NR          448                               // nodes per range
#define NRANGE      ((N_NODES + NR - 1) / NR)         // 112
#define NSLICE      4
#define SLICE_E     ((N_EDGES + NSLICE - 1) / NSLICE) // 200000
#define QCAP        1024                              // per-wave queue (u32)
#define AGG_THREADS 512

// ---------------------------------------------------------------------------
// agg_kernel: block = (node range, edge slice). Scan slice indices, ballot-
// compact in-range endpoints into per-wave LDS queues, drain 8-deep into a
// 448x64 LDS accumulator (ds_add_f32), flush to partials[slice].
// LDS: (448+1)*64*4 = 114,944 + 8*1024*4 = 32,768 -> 144.3 KB, 1 block/CU.
// ---------------------------------------------------------------------------
__global__ __launch_bounds__(AGG_THREADS, 1) void agg_kernel(
    const float* __restrict__ edges,
    const int* __restrict__ senders,
    const int* __restrict__ receivers,
    float* __restrict__ partials)          // [NSLICE][N_NODES][D]
{
    __shared__ float sagg[(NR + 1) * D];          // +1 dummy row for pad drains
    __shared__ unsigned int squeue[8 * QCAP];

    const int t     = threadIdx.x;
    const int lane  = t & 63;
    const int wid   = t >> 6;                     // 0..7
    const int range = blockIdx.x / NSLICE;
    const int slice = blockIdx.x % NSLICE;
    const int node0 = range * NR;
    const int ebeg  = slice * SLICE_E;
    const int eend  = min(N_EDGES, ebeg + SLICE_E);

    for (int i = t; i < NR * (D / 4); i += AGG_THREADS)
        reinterpret_cast<float4*>(sagg)[i] = make_float4(0.f, 0.f, 0.f, 0.f);
    __syncthreads();

    unsigned int* wq = &squeue[wid * QCAP];
    int qcnt = 0;

    auto drain_all = [&]() {
        const int padded = (qcnt + 7) & ~7;
        if (lane < padded - qcnt)                  // pad with dummy-row entries
            wq[qcnt + lane] = (0u << 10) | (unsigned)NR;
        for (int k = 0; k < padded; k += 8) {
            unsigned a[8]; float v[8];
            #pragma unroll
            for (int u = 0; u < 8; ++u) a[u] = wq[k + u];          // LDS broadcast
            #pragma unroll
            for (int u = 0; u < 8; ++u)                            // 8 indep loads
                v[u] = edges[(size_t)(a[u] >> 10) * D + lane];
            #pragma unroll
            for (int u = 0; u < 8; ++u)
                atomicAdd(&sagg[(a[u] & 1023u) * D + lane], v[u]); // ds_add_f32
        }
        qcnt = 0;
    };

    // scan: 8 waves stride chunks of 64; unroll 8 chunks for load MLP
    const int nchunks = (eend - ebeg + 64 * 8 - 1) / (64 * 8);  // per-wave count
    for (int i = 0; i < nchunks; i += 8) {
        int sv[8], rv[8], ix[8];
        #pragma unroll
        for (int u = 0; u < 8; ++u) {
            const int idx = ebeg + (wid + 8 * (i + u)) * 64 + lane;
            ix[u] = idx;
            const bool ok = idx < eend;
            sv[u] = ok ? senders[idx]   : 0x7fffffff;
            rv[u] = ok ? receivers[idx] : 0x7fffffff;
        }
        #pragma unroll
        for (int u = 0; u < 8; ++u) {
            {   // senders
                const unsigned ln = (unsigned)(sv[u] - node0);
                const bool hit = ln < (unsigned)NR;
                const unsigned long long m = __ballot(hit);
                if (hit) {
                    const int pos = qcnt + __popcll(m & ((1ull << lane) - 1ull));
                    wq[pos] = ((unsigned)ix[u] << 10) | ln;
                }
                qcnt += __popcll(m);
            }
            {   // receivers
                const unsigned ln = (unsigned)(rv[u] - node0);
                const bool hit = ln < (unsigned)NR;
                const unsigned long long m = __ballot(hit);
                if (hit) {
                    const int pos = qcnt + __popcll(m & ((1ull << lane) - 1ull));
                    wq[pos] = ((unsigned)ix[u] << 10) | ln;
                }
                qcnt += __popcll(m);
            }
            if (qcnt >= QCAP - 128) drain_all();
        }
    }
    drain_all();
    __syncthreads();

    // flush LDS accumulator -> partials[slice]
    for (int i = t; i < NR * (D / 4); i += AGG_THREADS) {
        const int row = i >> 4, c = i & 15;
        const int node = node0 + row;
        if (node < N_NODES) {
            const float4 vv = *reinterpret_cast<const float4*>(&sagg[row * D + c * 4]);
            reinterpret_cast<float4*>(partials)
                [(size_t)slice * N_NODES * (D / 4) + (size_t)node * (D / 4) + c] = vv;
        }
    }
}

// ---------------------------------------------------------------------------
// reduce: agg = sum of NSLICE partials (streaming float4)
// ---------------------------------------------------------------------------
__global__ __launch_bounds__(256) void reduce_kernel(
    const float4* __restrict__ p, float4* __restrict__ agg)
{
    const size_t NF4 = (size_t)N_NODES * (D / 4);     // 800000
    const size_t i = (size_t)blockIdx.x * 256 + threadIdx.x;
    if (i < NF4) {
        float4 a = p[i];
        float4 b = p[i + NF4];
        float4 c = p[i + 2 * NF4];
        float4 d = p[i + 3 * NF4];
        float4 o;
        o.x = (a.x + b.x) + (c.x + d.x);
        o.y = (a.y + b.y) + (c.y + d.y);
        o.z = (a.z + b.z) + (c.z + d.z);
        o.w = (a.w + b.w) + (c.w + d.w);
        agg[i] = o;
    }
}

// ---------------------------------------------------------------------------
// GEMM1: h = relu([agg|nodes] @ W1 + b1) -> hbuf [N][256] f32  (round-4)
// ---------------------------------------------------------------------------
__global__ __launch_bounds__(256, 2) void gemm1_kernel(
    const float* __restrict__ agg,
    const float* __restrict__ nodes,
    const float* __restrict__ W1,     // [128][256]
    const float* __restrict__ b1,     // [256]
    float* __restrict__ hbuf)         // [N][256]
{
    __shared__ __align__(16) float xs[MB1][DIN + 4];
    __shared__ __align__(16) float wls[KC1][HID];

    const int t = threadIdx.x;
    const int node0 = blockIdx.x * MB1;
    const int gn = t >> 5;
    const int gj = t & 31;

    for (int f = t; f < MB1 * 32; f += 256) {
        int n = f >> 5, c = f & 31;
        int node = node0 + n;
        float4 v = make_float4(0.f, 0.f, 0.f, 0.f);
        if (node < N_NODES)
            v = (c < 16) ? reinterpret_cast<const float4*>(agg   + (size_t)node * D)[c]
                         : reinterpret_cast<const float4*>(nodes + (size_t)node * D)[c - 16];
        *reinterpret_cast<float4*>(&xs[n][c * 4]) = v;
    }

    float acc[8][8];
    #pragma unroll
    for (int i = 0; i < 8; ++i)
        #pragma unroll
        for (int c = 0; c < 8; ++c) acc[i][c] = 0.f;

    for (int kc = 0; kc < DIN; kc += KC1) {
        __syncthreads();
        for (int f = t; f < KC1 * 64; f += 256) {
            int kk = f >> 6, c = f & 63;
            *reinterpret_cast<float4*>(&wls[kk][c * 4]) =
                reinterpret_cast<const float4*>(W1 + (size_t)(kc + kk) * HID)[c];
        }
        __syncthreads();

        #pragma unroll
        for (int k4 = 0; k4 < KC1; k4 += 4) {
            float4 xv[8];
            #pragma unroll
            for (int i = 0; i < 8; ++i)
                xv[i] = *reinterpret_cast<const float4*>(&xs[8 * gn + i][kc + k4]);
            float wv[4][8];
            #pragma unroll
            for (int kk = 0; kk < 4; ++kk)
                #pragma unroll
                for (int c = 0; c < 8; ++c) wv[kk][c] = wls[k4 + kk][gj + 32 * c];
            #pragma unroll
            for (int i = 0; i < 8; ++i)
                #pragma unroll
                for (int c = 0; c < 8; ++c) {
                    acc[i][c] = fmaf(xv[i].x, wv[0][c], acc[i][c]);
                    acc[i][c] = fmaf(xv[i].y, wv[1][c], acc[i][c]);
                    acc[i][c] = fmaf(xv[i].z, wv[2][c], acc[i][c]);
                    acc[i][c] = fmaf(xv[i].w, wv[3][c], acc[i][c]);
                }
        }
    }

    float bb[8];
    #pragma unroll
    for (int c = 0; c < 8; ++c) bb[c] = b1[gj + 32 * c];
    #pragma unroll
    for (int i = 0; i < 8; ++i) {
        const int node = node0 + 8 * gn + i;
        if (node < N_NODES) {
            #pragma unroll
            for (int c = 0; c < 8; ++c)
                hbuf[(size_t)node * HID + gj + 32 * c] = fmaxf(acc[i][c] + bb[c], 0.f);
        }
    }
}

// ---------------------------------------------------------------------------
// GEMM2: out = hbuf @ W2 + b2  (round-4)
// ---------------------------------------------------------------------------
__global__ __launch_bounds__(256, 4) void gemm2_kernel(
    const float* __restrict__ hbuf,
    const float* __restrict__ W2,
    const float* __restrict__ b2,
    float* __restrict__ out)
{
    __shared__ __align__(16) float hs[MB2][KC2 + 4];
    __shared__ __align__(16) float w2s[KC2][D + 4];

    const int t = threadIdx.x;
    const int node0 = blockIdx.x * MB2;
    const int tn = t >> 4;
    const int td = t & 15;

    float acc[4][4];
    #pragma unroll
    for (int i = 0; i < 4; ++i)
        #pragma unroll
        for (int j = 0; j < 4; ++j) acc[i][j] = 0.f;

    for (int kc = 0; kc < HID; kc += KC2) {
        __syncthreads();
        for (int f = t; f < MB2 * 8; f += 256) {
            int n = f >> 3, c = f & 7;
            int node = node0 + n;
            float4 v = make_float4(0.f, 0.f, 0.f, 0.f);
            if (node < N_NODES)
                v = reinterpret_cast<const float4*>(hbuf + (size_t)node * HID + kc)[c];
            *reinterpret_cast<float4*>(&hs[n][c * 4]) = v;
        }
        for (int f = t; f < KC2 * 16; f += 256) {
            int kk = f >> 4, c = f & 15;
            *reinterpret_cast<float4*>(&w2s[kk][c * 4]) =
                reinterpret_cast<const float4*>(W2 + (size_t)(kc + kk) * D)[c];
        }
        __syncthreads();

        #pragma unroll
        for (int k4 = 0; k4 < KC2; k4 += 4) {
            float4 hv[4];
            #pragma unroll
            for (int i = 0; i < 4; ++i)
                hv[i] = *reinterpret_cast<const float4*>(&hs[4 * tn + i][k4]);
            float4 wv[4];
            #pragma unroll
            for (int kk = 0; kk < 4; ++kk)
                wv[kk] = *reinterpret_cast<const float4*>(&w2s[k4 + kk][4 * td]);
            #pragma unroll
            for (int i = 0; i < 4; ++i) {
                acc[i][0] = fmaf(hv[i].x, wv[0].x, acc[i][0]);
                acc[i][1] = fmaf(hv[i].x, wv[0].y, acc[i][1]);
                acc[i][2] = fmaf(hv[i].x, wv[0].z, acc[i][2]);
                acc[i][3] = fmaf(hv[i].x, wv[0].w, acc[i][3]);
                acc[i][0] = fmaf(hv[i].y, wv[1].x, acc[i][0]);
                acc[i][1] = fmaf(hv[i].y, wv[1].y, acc[i][1]);
                acc[i][2] = fmaf(hv[i].y, wv[1].z, acc[i][2]);
                acc[i][3] = fmaf(hv[i].y, wv[1].w, acc[i][3]);
                acc[i][0] = fmaf(hv[i].z, wv[2].x, acc[i][0]);
                acc[i][1] = fmaf(hv[i].z, wv[2].y, acc[i][1]);
                acc[i][2] = fmaf(hv[i].z, wv[2].z, acc[i][2]);
                acc[i][3] = fmaf(hv[i].z, wv[2].w, acc[i][3]);
                acc[i][0] = fmaf(hv[i].w, wv[3].x, acc[i][0]);
                acc[i][1] = fmaf(hv[i].w, wv[3].y, acc[i][1]);
                acc[i][2] = fmaf(hv[i].w, wv[3].z, acc[i][2]);
                acc[i][3] = fmaf(hv[i].w, wv[3].w, acc[i][3]);
            }
        }
    }

    const float4 bb = *reinterpret_cast<const float4*>(b2 + 4 * td);
    #pragma unroll
    for (int i = 0; i < 4; ++i) {
        const int node = node0 + 4 * tn + i;
        if (node < N_NODES) {
            float4 o = make_float4(acc[i][0] + bb.x, acc[i][1] + bb.y,
                                   acc[i][2] + bb.z, acc[i][3] + bb.w);
            reinterpret_cast<float4*>(out + (size_t)node * D)[td] = o;
        }
    }
}

// ---------------------------------------------------------------------------
// Fallbacks (tiny ws): atomic scatter + fused MLP
// ---------------------------------------------------------------------------
__global__ __launch_bounds__(256) void scatter_kernel(
    const float* __restrict__ edges,
    const int* __restrict__ senders,
    const int* __restrict__ receivers,
    float* __restrict__ agg)
{
    int tid = blockIdx.x * 256 + threadIdx.x;
    int e = tid >> 4;
    int c = (tid & 15) << 2;
    if (e >= N_EDGES) return;
    const float4 v = *reinterpret_cast<const float4*>(edges + (long)e * D + c);
    int s = senders[e] * D + c;
    int r = receivers[e] * D + c;
    atomicAdd(&agg[s + 0], v.x); atomicAdd(&agg[s + 1], v.y);
    atomicAdd(&agg[s + 2], v.z); atomicAdd(&agg[s + 3], v.w);
    atomicAdd(&agg[r + 0], v.x); atomicAdd(&agg[r + 1], v.y);
    atomicAdd(&agg[r + 2], v.z); atomicAdd(&agg[r + 3], v.w);
}

__global__ __launch_bounds__(256, 2) void mlp_kernel(
    const float* __restrict__ agg, const float* __restrict__ nodes,
    const float* __restrict__ W1, const float* __restrict__ b1,
    const float* __restrict__ W2, const float* __restrict__ b2,
    float* __restrict__ out)
{
    __shared__ __align__(16) float x_lds[NB][DIN];
    __shared__ __align__(16) float h_lds[NB][HID];
    const int t = threadIdx.x;
    const int node0 = blockIdx.x * NB;

    for (int f = t; f < NB * DIN / 4; f += 256) {
        int n = f >> 5, c = f & 31;
        int node = node0 + n;
        float4 v = make_float4(0.f, 0.f, 0.f, 0.f);
        if (node < N_NODES) {
            const float* src = (c < 16) ? (agg   + (size_t)node * D + c * 4)
                                        : (nodes + (size_t)node * D + (c - 16) * 4);
            v = *reinterpret_cast<const float4*>(src);
        }
        *reinterpret_cast<float4*>(&x_lds[n][c * 4]) = v;
    }
    float w1c[DIN];
    #pragma unroll
    for (int k = 0; k < DIN; ++k) w1c[k] = W1[(size_t)k * HID + t];
    const float bias1 = b1[t];
    __syncthreads();

    for (int n = 0; n < NB; ++n) {
        const float4* xr = reinterpret_cast<const float4*>(x_lds[n]);
        float a0 = 0.f, a1 = 0.f, a2 = 0.f, a3 = 0.f;
        #pragma unroll
        for (int k4 = 0; k4 < 32; ++k4) {
            float4 x = xr[k4];
            a0 = fmaf(w1c[4*k4 + 0], x.x, a0);
            a1 = fmaf(w1c[4*k4 + 1], x.y, a1);
            a2 = fmaf(w1c[4*k4 + 2], x.z, a2);
            a3 = fmaf(w1c[4*k4 + 3], x.w, a3);
        }
        h_lds[n][t] = fmaxf(bias1 + ((a0 + a1) + (a2 + a3)), 0.0f);
    }
    __syncthreads();

    const int d  = t & 63;
    const int ng = t >> 6;
    float acc2[8];
    #pragma unroll
    for (int i = 0; i < 8; ++i) acc2[i] = 0.0f;
    for (int j = 0; j < HID; j += 4) {
        const float w0 = W2[(j + 0) * D + d];
        const float w1 = W2[(j + 1) * D + d];
        const float w2 = W2[(j + 2) * D + d];
        const float w3 = W2[(j + 3) * D + d];
        #pragma unroll
        for (int i = 0; i < 8; ++i) {
            const int n = ng + 4 * i;
            const float4 h4 = *reinterpret_cast<const float4*>(&h_lds[n][j]);
            acc2[i] = fmaf(w0, h4.x, acc2[i]);
            acc2[i] = fmaf(w1, h4.y, acc2[i]);
            acc2[i] = fmaf(w2, h4.z, acc2[i]);
            acc2[i] = fmaf(w3, h4.w, acc2[i]);
        }
    }
    const float bias2 = b2[d];
    #pragma unroll
    for (int i = 0; i < 8; ++i) {
        const int n = ng + 4 * i;
        const int node = node0 + n;
        if (node < N_NODES) out[(size_t)node * D + d] = acc2[i] + bias2;
    }
}

// ---------------------------------------------------------------------------
extern "C" void kernel_launch(void* const* d_in, const int* in_sizes, int n_in,
                              void* d_out, int out_size, void* d_ws, size_t ws_size,
                              hipStream_t stream)
{
    const float* nodes     = (const float*)d_in[0];
    const float* edges     = (const float*)d_in[1];
    const int*   senders   = (const int*)  d_in[2];
    const int*   receivers = (const int*)  d_in[3];
    const float* W1        = (const float*)d_in[4];
    const float* b1        = (const float*)d_in[5];
    const float* W2        = (const float*)d_in[6];
    const float* b2        = (const float*)d_in[7];
    float* out = (float*)d_out;

    // ws layout: agg [3.2M f32] | partials [4 x 3.2M f32] (aliased with hbuf [12.8M f32])
    float* agg      = (float*)d_ws;
    float* partials = agg + (size_t)N_NODES * D;       // 12.8 MB offset
    float* hbuf     = partials;                        // alias: partials dead after reduce
    const size_t need_bytes =
        ((size_t)N_NODES * D + (size_t)NSLICE * N_NODES * D) * sizeof(float); // 64 MB
    // hbuf needs NSLICE*N*D == N*HID floats: identical size, alias is exact.

    const int gemm_blocks = (N_NODES + MB1 - 1) / MB1;  // 782

    if (ws_size >= need_bytes) {
        agg_kernel<<<NRANGE * NSLICE, AGG_THREADS, 0, stream>>>(
            edges, senders, receivers, partials);
        reduce_kernel<<<(N_NODES * (D / 4) + 255) / 256, 256, 0, stream>>>(
            (const float4*)partials, (float4*)agg);
        gemm1_kernel<<<gemm_blocks, 256, 0, stream>>>(agg, nodes, W1, b1, hbuf);
        gemm2_kernel<<<gemm_blocks, 256, 0, stream>>>(hbuf, W2, b2, out);
    } else {
        // minimal-ws fallback: atomic scatter + fused MLP
        hipMemsetAsync(agg, 0, (size_t)N_NODES * D * sizeof(float), stream);
        scatter_kernel<<<(N_EDGES * 16) / 256, 256, 0, stream>>>(edges, senders, receivers, agg);
        mlp_kernel<<<(N_NODES + NB - 1) / NB, 256, 0, stream>>>(
            agg, nodes, W1, b1, W2, b2, out);
    }
}